// Round 1
// baseline (414.292 us; speedup 1.0000x reference)
//
#include <hip/hip_runtime.h>
#include <hip/hip_bf16.h>

#define Bb 4
#define Hh 16
#define Ss 2048
#define Dd 64
#define QBLK 64
#define KVB 64
#define LDK 72   // padded LDS leading dim (elements): +8 bf16 = +16B -> 2-way bank alias (free)

using f32x4 = __attribute__((ext_vector_type(4))) float;
using s16x8 = __attribute__((ext_vector_type(8))) short;

// fp32 -> bf16 (round-to-nearest-even), bit pattern in a short
__device__ __forceinline__ short f2bf(float f) {
    union { float f; uint32_t u; } c; c.f = f;
    uint32_t u = c.u;
    u += 0x7FFFu + ((u >> 16) & 1u);
    return (short)(u >> 16);
}

__global__ __launch_bounds__(256)
void attn_fwd_kernel(const float* __restrict__ Qg, const float* __restrict__ Kg,
                     const float* __restrict__ Vg, float* __restrict__ Og) {
    const int q0   = blockIdx.x * QBLK;
    const int bh   = blockIdx.y;
    const int tid  = threadIdx.x;
    const int wid  = tid >> 6;     // wave 0..3 -> q rows [q0+16*wid, +16)
    const int lane = tid & 63;
    const int l16  = lane & 15;    // MFMA col / A-row index
    const int lg   = lane >> 4;    // 0..3

    __shared__ short Ks[KVB][LDK];     // K tile: [kv][d]
    __shared__ short Vs[Dd][LDK];      // V tile transposed: [d][kv]
    __shared__ short Ps[4][16][LDK];   // per-wave P bounce: [qrow][kv]

    const size_t base = (size_t)bh * Ss * Dd;
    const float* Qp = Qg + base;
    const float* Kp = Kg + base;
    const float* Vp = Vg + base;
    float*       Op = Og + base;

    // ---- load Q fragments for this wave's 16 rows, pre-scaled by 1/sqrt(D) ----
    // A-frag layout: row = l16, k = lg*8 + j  (frag f covers k in [32f, 32f+32))
    s16x8 qf[2];
    {
        const int qrow = q0 + wid * 16 + l16;
        const float* qr = Qp + (size_t)qrow * Dd + lg * 8;
        #pragma unroll
        for (int f = 0; f < 2; ++f) {
            const float4* q4 = reinterpret_cast<const float4*>(qr + f * 32);
            float4 a = q4[0], b = q4[1];
            qf[f][0] = f2bf(a.x * 0.125f); qf[f][1] = f2bf(a.y * 0.125f);
            qf[f][2] = f2bf(a.z * 0.125f); qf[f][3] = f2bf(a.w * 0.125f);
            qf[f][4] = f2bf(b.x * 0.125f); qf[f][5] = f2bf(b.y * 0.125f);
            qf[f][6] = f2bf(b.z * 0.125f); qf[f][7] = f2bf(b.w * 0.125f);
        }
    }

    f32x4 acc[4] = {f32x4{0,0,0,0}, f32x4{0,0,0,0}, f32x4{0,0,0,0}, f32x4{0,0,0,0}};
    float mrow[4] = {-1e30f, -1e30f, -1e30f, -1e30f};
    float lrow[4] = {0.f, 0.f, 0.f, 0.f};

    // staging decomposition: 256 threads cover 32 rows x 8 feat-blocks per iter
    const int srow = tid >> 3;        // 0..31
    const int scol = (tid & 7) * 8;   // feat block base

    for (int kv0 = 0; kv0 <= q0; kv0 += KVB) {
        __syncthreads();   // previous iteration's LDS reads complete
        #pragma unroll
        for (int it = 0; it < 2; ++it) {
            const int row = srow + it * 32;    // kv index within tile
            const float4* k4 = reinterpret_cast<const float4*>(Kp + (size_t)(kv0 + row) * Dd + scol);
            float4 ka = k4[0], kb = k4[1];
            short tmp[8];
            tmp[0]=f2bf(ka.x); tmp[1]=f2bf(ka.y); tmp[2]=f2bf(ka.z); tmp[3]=f2bf(ka.w);
            tmp[4]=f2bf(kb.x); tmp[5]=f2bf(kb.y); tmp[6]=f2bf(kb.z); tmp[7]=f2bf(kb.w);
            *reinterpret_cast<s16x8*>(&Ks[row][scol]) = *reinterpret_cast<const s16x8*>(tmp);
            const float4* v4 = reinterpret_cast<const float4*>(Vp + (size_t)(kv0 + row) * Dd + scol);
            float4 va = v4[0], vb = v4[1];
            Vs[scol+0][row] = f2bf(va.x); Vs[scol+1][row] = f2bf(va.y);
            Vs[scol+2][row] = f2bf(va.z); Vs[scol+3][row] = f2bf(va.w);
            Vs[scol+4][row] = f2bf(vb.x); Vs[scol+5][row] = f2bf(vb.y);
            Vs[scol+6][row] = f2bf(vb.z); Vs[scol+7][row] = f2bf(vb.w);
        }
        __syncthreads();

        // ---- scores: S = (Q*scale) @ K^T, 4 col-tiles x (K=64 -> 2 MFMA) ----
        // B-frag for QK^T: col = kv = l16 (+16t), k = feat = lg*8+j (+32) -> contiguous in Ks
        f32x4 sc[4];
        #pragma unroll
        for (int t = 0; t < 4; ++t) {
            s16x8 kf0 = *reinterpret_cast<const s16x8*>(&Ks[t*16 + l16][lg*8]);
            s16x8 kf1 = *reinterpret_cast<const s16x8*>(&Ks[t*16 + l16][32 + lg*8]);
            f32x4 z = {0.f, 0.f, 0.f, 0.f};
            z     = __builtin_amdgcn_mfma_f32_16x16x32_bf16(qf[0], kf0, z, 0, 0, 0);
            sc[t] = __builtin_amdgcn_mfma_f32_16x16x32_bf16(qf[1], kf1, z, 0, 0, 0);
        }

        // causal mask: only the diagonal KV block has cols > rows
        if (kv0 == q0) {
            #pragma unroll
            for (int t = 0; t < 4; ++t) {
                const int col = kv0 + t * 16 + l16;
                #pragma unroll
                for (int r = 0; r < 4; ++r) {
                    const int row = q0 + wid * 16 + lg * 4 + r;
                    if (col > row) sc[t][r] = -1e30f;
                }
            }
        }

        // ---- online softmax (C-layout: row = lg*4+r, col = l16+16t) ----
        #pragma unroll
        for (int r = 0; r < 4; ++r) {
            float mx = fmaxf(fmaxf(sc[0][r], sc[1][r]), fmaxf(sc[2][r], sc[3][r]));
            mx = fmaxf(mx, __shfl_xor(mx, 1));
            mx = fmaxf(mx, __shfl_xor(mx, 2));
            mx = fmaxf(mx, __shfl_xor(mx, 4));
            mx = fmaxf(mx, __shfl_xor(mx, 8));
            const float newm = fmaxf(mrow[r], mx);
            const float corr = __expf(mrow[r] - newm);
            mrow[r] = newm;
            lrow[r] *= corr;
            acc[0][r] *= corr; acc[1][r] *= corr;
            acc[2][r] *= corr; acc[3][r] *= corr;
        }

        float rsum[4] = {0.f, 0.f, 0.f, 0.f};
        #pragma unroll
        for (int t = 0; t < 4; ++t) {
            #pragma unroll
            for (int r = 0; r < 4; ++r) {
                const float p = __expf(sc[t][r] - mrow[r]);   // masked -> exp(-huge) = 0
                rsum[r] += p;
                Ps[wid][lg*4 + r][t*16 + l16] = f2bf(p);
            }
        }
        #pragma unroll
        for (int r = 0; r < 4; ++r) {
            float s = rsum[r];
            s += __shfl_xor(s, 1);
            s += __shfl_xor(s, 2);
            s += __shfl_xor(s, 4);
            s += __shfl_xor(s, 8);
            lrow[r] += s;
        }

        // ---- PV: O += P @ V ----
        // A-frag from per-wave P bounce (row = l16, k = kv = lg*8+j)
        s16x8 pf0 = *reinterpret_cast<const s16x8*>(&Ps[wid][l16][lg*8]);
        s16x8 pf1 = *reinterpret_cast<const s16x8*>(&Ps[wid][l16][32 + lg*8]);
        #pragma unroll
        for (int c = 0; c < 4; ++c) {
            // B-frag: col = feat = 16c + l16, k = kv = lg*8+j (+32) -> contiguous in Vs
            s16x8 vf0 = *reinterpret_cast<const s16x8*>(&Vs[c*16 + l16][lg*8]);
            s16x8 vf1 = *reinterpret_cast<const s16x8*>(&Vs[c*16 + l16][32 + lg*8]);
            acc[c] = __builtin_amdgcn_mfma_f32_16x16x32_bf16(pf0, vf0, acc[c], 0, 0, 0);
            acc[c] = __builtin_amdgcn_mfma_f32_16x16x32_bf16(pf1, vf1, acc[c], 0, 0, 0);
        }
    }

    // ---- epilogue: O = acc / l ----
    #pragma unroll
    for (int r = 0; r < 4; ++r) {
        const float inv = 1.0f / lrow[r];
        const int row = q0 + wid * 16 + lg * 4 + r;
        float* op = Op + (size_t)row * Dd + l16;
        op[0]  = acc[0][r] * inv;
        op[16] = acc[1][r] * inv;
        op[32] = acc[2][r] * inv;
        op[48] = acc[3][r] * inv;
    }
}

extern "C" void kernel_launch(void* const* d_in, const int* in_sizes, int n_in,
                              void* d_out, int out_size, void* d_ws, size_t ws_size,
                              hipStream_t stream) {
    const float* Q = (const float*)d_in[0];
    const float* K = (const float*)d_in[1];
    const float* V = (const float*)d_in[2];
    float* O = (float*)d_out;
    dim3 grid(Ss / QBLK, Bb * Hh);
    attn_fwd_kernel<<<grid, 256, 0, stream>>>(Q, K, V, O);
}

// Round 2
// 279.385 us; speedup vs baseline: 1.4829x; 1.4829x over previous
//
#include <hip/hip_runtime.h>
#include <hip/hip_bf16.h>
#include <stdint.h>

#define Ss 2048
#define Dd 64
#define QBLK 128   // 4 waves x 32 q-rows
#define KVB 64

using f32x16 = __attribute__((ext_vector_type(16))) float;
using s16x8  = __attribute__((ext_vector_type(8))) short;

__device__ __forceinline__ short f2bf(float f) {
    union { float f; uint32_t u; } c; c.f = f;
    uint32_t u = c.u;
    u += 0x7FFFu + ((u >> 16) & 1u);
    return (short)(u >> 16);
}
__device__ __forceinline__ uint32_t packbf(float lo, float hi) {
    return (uint32_t)(uint16_t)f2bf(lo) | ((uint32_t)(uint16_t)f2bf(hi) << 16);
}

union U4 { uint32_t u[4]; s16x8 v; };

__global__ __launch_bounds__(256)
void attn_fwd_kernel(const float* __restrict__ Qg, const float* __restrict__ Kg,
                     const float* __restrict__ Vg, float* __restrict__ Og) {
    const int qb   = (int)gridDim.x - 1 - (int)blockIdx.x;  // long blocks first
    const int q0   = qb * QBLK;
    const int bh   = blockIdx.y;
    const int tid  = threadIdx.x;
    const int w    = tid >> 6;
    const int l    = tid & 63;
    const int l31  = l & 31;
    const int hi   = l >> 5;
    const int qmin = q0 + 32 * w;
    const int qrow = qmin + l31;

    __shared__ short Ks[KVB * Dd];   // [kv][d], XOR-swizzled
    __shared__ short Vs[Dd * KVB];   // V^T: [d][kv], XOR-swizzled
    __shared__ float ob[64][68];     // epilogue bounce (padded)

    const size_t base = (size_t)bh * Ss * Dd;
    const float* Qp = Qg + base;
    const float* Kp = Kg + base;
    const float* Vp = Vg + base;
    float*       Op = Og + base;

    // ---- Q fragments (B-operand of swapped QK^T), scaled to log2 domain ----
    const float SCALE = 0.18033688011112042f;  // (1/sqrt(64)) * log2(e)
    s16x8 qf[4];
    {
        const float* qp = Qp + (size_t)qrow * Dd;
        #pragma unroll
        for (int kt = 0; kt < 4; ++kt) {
            const float4 a = *(const float4*)(qp + kt*16 + hi*8);
            const float4 b = *(const float4*)(qp + kt*16 + hi*8 + 4);
            s16x8 q8;
            q8[0]=f2bf(a.x*SCALE); q8[1]=f2bf(a.y*SCALE); q8[2]=f2bf(a.z*SCALE); q8[3]=f2bf(a.w*SCALE);
            q8[4]=f2bf(b.x*SCALE); q8[5]=f2bf(b.y*SCALE); q8[6]=f2bf(b.z*SCALE); q8[7]=f2bf(b.w*SCALE);
            qf[kt] = q8;
        }
    }

    f32x16 acc[2];   // O^T: row d-local, col q
    #pragma unroll
    for (int c = 0; c < 2; ++c)
        #pragma unroll
        for (int r = 0; r < 16; ++r) acc[c][r] = 0.f;
    float mrun = -1e30f, lrun = 0.f;

    // staging maps
    const int skv = tid >> 2;          // K row 0..63
    const int sd  = (tid & 3) * 16;    // K feat base
    const int vd  = tid & 63;          // V column (d)
    const int vo  = (tid >> 6) * 8;    // V kv-octet

    char* KB = (char*)Ks;
    char* VB = (char*)Vs;

    for (int kv0 = 0; kv0 < q0 + QBLK; kv0 += KVB) {
        __syncthreads();
        // ---- stage K: row-major, b128 writes, XOR swizzle ----
        {
            const float* kr = Kp + (size_t)(kv0 + skv) * Dd + sd;
            const float4 a  = *(const float4*)(kr);
            const float4 b  = *(const float4*)(kr + 4);
            const float4 c4 = *(const float4*)(kr + 8);
            const float4 d4 = *(const float4*)(kr + 12);
            s16x8 lo8, hi8;
            lo8[0]=f2bf(a.x);  lo8[1]=f2bf(a.y);  lo8[2]=f2bf(a.z);  lo8[3]=f2bf(a.w);
            lo8[4]=f2bf(b.x);  lo8[5]=f2bf(b.y);  lo8[6]=f2bf(b.z);  lo8[7]=f2bf(b.w);
            hi8[0]=f2bf(c4.x); hi8[1]=f2bf(c4.y); hi8[2]=f2bf(c4.z); hi8[3]=f2bf(c4.w);
            hi8[4]=f2bf(d4.x); hi8[5]=f2bf(d4.y); hi8[6]=f2bf(d4.z); hi8[7]=f2bf(d4.w);
            const int bse = skv*128 + sd*2;
            const int sw  = (skv & 7) << 4;
            *(s16x8*)(KB + ((bse)      ^ sw)) = lo8;
            *(s16x8*)(KB + ((bse + 16) ^ sw)) = hi8;
        }
        // ---- stage V^T: coalesced column reads -> b128 row writes, XOR swizzle ----
        #pragma unroll
        for (int h = 0; h < 2; ++h) {
            const int kvb = h * 32 + vo;
            const float* vr = Vp + (size_t)(kv0 + kvb) * Dd + vd;
            float vv[8];
            #pragma unroll
            for (int r = 0; r < 8; ++r) vv[r] = vr[(size_t)r * Dd];
            s16x8 v8;
            #pragma unroll
            for (int r = 0; r < 8; ++r) v8[r] = f2bf(vv[r]);
            *(s16x8*)(VB + ((vd*128 + kvb*2) ^ ((vd & 7) << 4))) = v8;
        }
        __syncthreads();

        if (kv0 <= qmin + 31) {   // wave-uniform; no barriers inside
            // ---- S^T = K @ Q^T  (log2 domain) ----
            f32x16 st[2];
            #pragma unroll
            for (int t2 = 0; t2 < 2; ++t2) {
                #pragma unroll
                for (int r = 0; r < 16; ++r) st[t2][r] = 0.f;
                const int kvr = t2*32 + l31;
                const int sw  = (kvr & 7) << 4;
                #pragma unroll
                for (int kt = 0; kt < 4; ++kt) {
                    const s16x8 kf = *(const s16x8*)(KB + ((kvr*128 + kt*32 + hi*16) ^ sw));
                    st[t2] = __builtin_amdgcn_mfma_f32_32x32x16_bf16(kf, qf[kt], st[t2], 0, 0, 0);
                }
            }
            // ---- causal mask (only near diagonal) ----
            if (kv0 + 63 > qmin) {
                #pragma unroll
                for (int t2 = 0; t2 < 2; ++t2)
                    #pragma unroll
                    for (int r = 0; r < 16; ++r) {
                        const int kvloc = 32*t2 + (r & 3) + 8*(r >> 2) + 4*hi;
                        if (kv0 + kvloc > qrow) st[t2][r] = -1e30f;
                    }
            }
            // ---- online softmax: in-lane tree + one lane^32 exchange ----
            float pmax = st[0][0];
            #pragma unroll
            for (int t2 = 0; t2 < 2; ++t2)
                #pragma unroll
                for (int r = 0; r < 16; ++r) pmax = fmaxf(pmax, st[t2][r]);
            pmax = fmaxf(pmax, __shfl_xor(pmax, 32));
            const float newm = fmaxf(mrun, pmax);
            const float corr = exp2f(mrun - newm);
            mrun = newm;
            float psum = 0.f;
            #pragma unroll
            for (int t2 = 0; t2 < 2; ++t2)
                #pragma unroll
                for (int r = 0; r < 16; ++r) {
                    const float p = exp2f(st[t2][r] - mrun);
                    st[t2][r] = p;
                    psum += p;
                }
            psum += __shfl_xor(psum, 32);
            lrun = lrun * corr + psum;
            #pragma unroll
            for (int c = 0; c < 2; ++c)
                #pragma unroll
                for (int r = 0; r < 16; ++r) acc[c][r] *= corr;

            // ---- pack P rows to bf16 pairs (per 4-element reg groups) ----
            uint32_t P4[2][4][2];
            #pragma unroll
            for (int t2 = 0; t2 < 2; ++t2)
                #pragma unroll
                for (int rq = 0; rq < 4; ++rq) {
                    P4[t2][rq][0] = packbf(st[t2][4*rq+0], st[t2][4*rq+1]);
                    P4[t2][rq][1] = packbf(st[t2][4*rq+2], st[t2][4*rq+3]);
                }
            // ---- PV: O^T += V^T @ P^T ----
            #pragma unroll
            for (int kt = 0; kt < 4; ++kt) {
                const int t2 = kt >> 1, r0 = 2*(kt & 1), r1 = r0 + 1;
                // send the 4-group my lane^32 partner needs; receive mine
                const uint32_t s0 = hi ? P4[t2][r0][0] : P4[t2][r1][0];
                const uint32_t s1 = hi ? P4[t2][r0][1] : P4[t2][r1][1];
                const uint32_t x0 = __shfl_xor(s0, 32);
                const uint32_t x1 = __shfl_xor(s1, 32);
                const uint32_t o0 = hi ? P4[t2][r1][0] : P4[t2][r0][0];
                const uint32_t o1 = hi ? P4[t2][r1][1] : P4[t2][r0][1];
                U4 pa;
                pa.u[0] = hi ? x0 : o0;
                pa.u[1] = hi ? x1 : o1;
                pa.u[2] = hi ? o0 : x0;
                pa.u[3] = hi ? o1 : x1;
                #pragma unroll
                for (int c = 0; c < 2; ++c) {
                    const int d  = 32*c + l31;
                    const s16x8 vf = *(const s16x8*)(VB + ((d*128 + kt*32 + hi*16) ^ ((d & 7) << 4)));
                    acc[c] = __builtin_amdgcn_mfma_f32_32x32x16_bf16(vf, pa.v, acc[c], 0, 0, 0);
                }
            }
        }
    }

    // ---- epilogue: O^T -> O via padded LDS bounce, coalesced float4 stores ----
    const float inv = 1.0f / lrun;
    #pragma unroll
    for (int chunk = 0; chunk < 2; ++chunk) {
        __syncthreads();
        if ((w >> 1) == chunk) {
            const int qloc = 32*(w & 1) + l31;
            #pragma unroll
            for (int c = 0; c < 2; ++c)
                #pragma unroll
                for (int r = 0; r < 16; ++r) {
                    const int d = 32*c + (r & 3) + 8*(r >> 2) + 4*hi;
                    ob[qloc][d] = acc[c][r] * inv;
                }
        }
        __syncthreads();
        #pragma unroll
        for (int i = 0; i < 4; ++i) {
            const int idx = i*256 + tid;
            const int row = idx >> 4;
            const int c4  = (idx & 15) * 4;
            const float4 v = *(const float4*)&ob[row][c4];
            *(float4*)(Op + (size_t)(q0 + chunk*64 + row) * Dd + c4) = v;
        }
    }
}

extern "C" void kernel_launch(void* const* d_in, const int* in_sizes, int n_in,
                              void* d_out, int out_size, void* d_ws, size_t ws_size,
                              hipStream_t stream) {
    const float* Q = (const float*)d_in[0];
    const float* K = (const float*)d_in[1];
    const float* V = (const float*)d_in[2];
    float* O = (float*)d_out;
    dim3 grid(Ss / QBLK, 64);
    attn_fwd_kernel<<<grid, 256, 0, stream>>>(Q, K, V, O);
}

// Round 3
// 204.264 us; speedup vs baseline: 2.0282x; 1.3678x over previous
//
#include <hip/hip_runtime.h>
#include <hip/hip_bf16.h>
#include <stdint.h>

#define Ss 2048
#define Dd 64
#define QBLK 128   // 4 waves x 32 q-rows
#define KVB 64
#define NBH 64     // B*H

using f32x16 = __attribute__((ext_vector_type(16))) float;
using s16x8  = __attribute__((ext_vector_type(8))) short;

#if __has_builtin(__builtin_amdgcn_exp2f)
#define EXP2(x) __builtin_amdgcn_exp2f(x)
#else
#define EXP2(x) exp2f(x)
#endif

__device__ __forceinline__ short f2bf(float f) {
    union { float f; uint32_t u; } c; c.f = f;
    uint32_t u = c.u;
    u += 0x7FFFu + ((u >> 16) & 1u);
    return (short)(u >> 16);
}
__device__ __forceinline__ uint32_t cvt_pk_bf16(float lo, float hi) {
    uint32_t r;
    asm("v_cvt_pk_bf16_f32 %0, %1, %2" : "=v"(r) : "v"(lo), "v"(hi));
    return r;
}
// (x,y) <- permlane32_swap(a,b): x = lo:a / hi:b[partner]; y = lo:a[partner] / hi:b
__device__ __forceinline__ void pl32swap(uint32_t a, uint32_t b, int hi,
                                         uint32_t& x, uint32_t& y) {
#if __has_builtin(__builtin_amdgcn_permlane32_swap)
    auto r = __builtin_amdgcn_permlane32_swap(a, b, false, false);
    x = r[0]; y = r[1];
#else
    const uint32_t as = (uint32_t)__shfl_xor((int)a, 32);
    const uint32_t bs = (uint32_t)__shfl_xor((int)b, 32);
    x = hi ? bs : a;
    y = hi ? b  : as;
#endif
}

// ---------------- prepass: K fp32 -> bf16 (same layout) ----------------
__global__ __launch_bounds__(256)
void cvt_k_kernel(const float* __restrict__ K, uint16_t* __restrict__ Kb) {
    const size_t i = ((size_t)blockIdx.x * 256 + threadIdx.x) * 8;
    const float4 a = *(const float4*)(K + i);
    const float4 b = *(const float4*)(K + i + 4);
    union { uint32_t u[4]; s16x8 v; } o;
    o.u[0] = cvt_pk_bf16(a.x, a.y); o.u[1] = cvt_pk_bf16(a.z, a.w);
    o.u[2] = cvt_pk_bf16(b.x, b.y); o.u[3] = cvt_pk_bf16(b.z, b.w);
    *(s16x8*)(Kb + i) = o.v;
}

// ---------------- prepass: V fp32 [bh][kv][d] -> V^T bf16 [bh][d][kv] ----------------
__global__ __launch_bounds__(256)
void tr_v_kernel(const float* __restrict__ V, uint16_t* __restrict__ Vt) {
    const int bh  = blockIdx.y;
    const int kv0 = blockIdx.x * 64;
    __shared__ float ts[64][65];
    const float* vp = V + (size_t)bh * Ss * Dd + (size_t)kv0 * Dd;
    {
        const int r = threadIdx.x >> 2;
        const int c = (threadIdx.x & 3) * 16;
        #pragma unroll
        for (int j = 0; j < 4; ++j)
            *(float4*)&ts[r][c + 4*j] = *(const float4*)(vp + (size_t)r * Dd + c + 4*j);
    }
    __syncthreads();
    const int d   = threadIdx.x >> 2;
    const int k16 = (threadIdx.x & 3) * 16;
    union { uint32_t u[8]; struct { s16x8 a, b; } s; } o;
    #pragma unroll
    for (int j = 0; j < 8; ++j)
        o.u[j] = cvt_pk_bf16(ts[k16 + 2*j][d], ts[k16 + 2*j + 1][d]);
    uint16_t* op = Vt + ((size_t)bh * Dd + d) * Ss + kv0 + k16;
    *(s16x8*)op       = o.s.a;
    *(s16x8*)(op + 8) = o.s.b;
}

// ---------------- main attention kernel (prepassed bf16 K, V^T) ----------------
__global__ __launch_bounds__(256, 4)
void attn_fwd_main(const float* __restrict__ Qg, const uint16_t* __restrict__ Kb,
                   const uint16_t* __restrict__ Vt, float* __restrict__ Og) {
    const int qb   = (int)gridDim.x - 1 - (int)blockIdx.x;  // long blocks first
    const int q0   = qb * QBLK;
    const int bh   = blockIdx.y;
    const int tid  = threadIdx.x;
    const int w    = tid >> 6;
    const int l    = tid & 63;
    const int l31  = l & 31;
    const int hi   = l >> 5;
    const int qmin = q0 + 32 * w;
    const int qrow = qmin + l31;

    __shared__ char smem[2 * 16384];   // 2 buffers x (K 8KB + V 8KB); epilogue aliases

    const float* Qp = Qg + (size_t)bh * Ss * Dd;
    const char*  Kp = (const char*)(Kb + (size_t)bh * Ss * Dd);
    const char*  Vp = (const char*)(Vt + (size_t)bh * Dd * Ss);
    float*       Op = Og + (size_t)bh * Ss * Dd;

    // ---- Q fragments (B-operand of swapped QK^T), scaled into log2 domain ----
    const float SCALE = 0.18033688011112042f;  // (1/sqrt(64)) * log2(e)
    s16x8 qf[4];
    {
        const float* qp = Qp + (size_t)qrow * Dd;
        #pragma unroll
        for (int kt = 0; kt < 4; ++kt) {
            const float4 a = *(const float4*)(qp + kt*16 + hi*8);
            const float4 b = *(const float4*)(qp + kt*16 + hi*8 + 4);
            union { uint32_t u[4]; s16x8 v; } q;
            q.u[0] = cvt_pk_bf16(a.x*SCALE, a.y*SCALE);
            q.u[1] = cvt_pk_bf16(a.z*SCALE, a.w*SCALE);
            q.u[2] = cvt_pk_bf16(b.x*SCALE, b.y*SCALE);
            q.u[3] = cvt_pk_bf16(b.z*SCALE, b.w*SCALE);
            qf[kt] = q.v;
        }
    }

    f32x16 acc[2];
    #pragma unroll
    for (int c = 0; c < 2; ++c)
        #pragma unroll
        for (int r = 0; r < 16; ++r) acc[c][r] = 0.f;
    float mrun = -1e30f, lrun = 0.f;

    const int nt = (q0 + QBLK) / KVB;
    const int jl = l;                 // lane within wave
    const int rK = jl >> 3;           // sub-row within 8-row chunk
    const int bX = (jl & 7) ^ rK;     // inverse-swizzled 16B block index

    // stage tile t into buffer buf (wave w stages chunks 2w, 2w+1 of K and V)
    auto STAGE = [&](int t, int buf) {
        char* Kd = smem + buf * 16384;
        char* Vd = Kd + 8192;
        #pragma unroll
        for (int c2 = 0; c2 < 2; ++c2) {
            const int c = 2 * w + c2;
            const int r = c * 8 + rK;
            const char* gk = Kp + (size_t)(t * KVB + r) * 128 + bX * 16;
            const char* gv = Vp + (size_t)r * (Ss * 2) + t * (KVB * 2) + bX * 16;
#if __has_builtin(__builtin_amdgcn_global_load_lds)
            __builtin_amdgcn_global_load_lds((const uint32_t*)gk, (uint32_t*)(Kd + c*1024), 16, 0, 0);
            __builtin_amdgcn_global_load_lds((const uint32_t*)gv, (uint32_t*)(Vd + c*1024), 16, 0, 0);
#else
            *(s16x8*)(Kd + c*1024 + jl*16) = *(const s16x8*)gk;
            *(s16x8*)(Vd + c*1024 + jl*16) = *(const s16x8*)gv;
#endif
        }
    };

    STAGE(0, 0);
    __syncthreads();
    int cur = 0;

    for (int t = 0; t < nt; ++t) {
        if (t + 1 < nt) STAGE(t + 1, cur ^ 1);
        const int kv0 = t * KVB;

        if (kv0 <= qmin + 31) {     // wave-uniform predicate; barriers stay outside
            const char* Kd = smem + cur * 16384;
            const char* Vd = Kd + 8192;

            // ---- S^T = K @ Q^T (log2 domain) ----
            f32x16 st[2];
            __builtin_amdgcn_s_setprio(1);
            #pragma unroll
            for (int t2 = 0; t2 < 2; ++t2) {
                #pragma unroll
                for (int r = 0; r < 16; ++r) st[t2][r] = 0.f;
                const int kvr = t2 * 32 + l31;
                const int sw  = (kvr & 7) << 4;
                #pragma unroll
                for (int kt = 0; kt < 4; ++kt) {
                    const s16x8 kf = *(const s16x8*)(Kd + ((kvr*128 + kt*32 + hi*16) ^ sw));
                    st[t2] = __builtin_amdgcn_mfma_f32_32x32x16_bf16(kf, qf[kt], st[t2], 0, 0, 0);
                }
            }
            __builtin_amdgcn_s_setprio(0);

            // ---- causal mask (diagonal tiles only) ----
            if (kv0 + 63 > qmin) {
                #pragma unroll
                for (int t2 = 0; t2 < 2; ++t2)
                    #pragma unroll
                    for (int r = 0; r < 16; ++r) {
                        const int kvloc = 32*t2 + (r & 3) + 8*(r >> 2) + 4*hi;
                        if (kv0 + kvloc > qrow) st[t2][r] = -1e30f;
                    }
            }

            // ---- online softmax, 4-way trees + one lane^32 exchange ----
            float mx0 = st[0][0], mx1 = st[0][1], mx2 = st[0][2], mx3 = st[0][3];
            #pragma unroll
            for (int t2 = 0; t2 < 2; ++t2)
                #pragma unroll
                for (int r = (t2 ? 0 : 4); r < 16; r += 4) {
                    mx0 = fmaxf(mx0, st[t2][r+0]); mx1 = fmaxf(mx1, st[t2][r+1]);
                    mx2 = fmaxf(mx2, st[t2][r+2]); mx3 = fmaxf(mx3, st[t2][r+3]);
                }
            float pmax = fmaxf(fmaxf(mx0, mx1), fmaxf(mx2, mx3));
            pmax = fmaxf(pmax, __shfl_xor(pmax, 32));

            // T13 defer-max: skip rescale while growth bounded (log2 THR = 11)
            if (!__all(pmax - mrun <= 11.f)) {
                const float newm = fmaxf(mrun, pmax);
                const float corr = EXP2(mrun - newm);
                mrun = newm;
                lrun *= corr;
                acc[0] *= corr;
                acc[1] *= corr;
            }

            float ps0 = 0.f, ps1 = 0.f, ps2 = 0.f, ps3 = 0.f;
            #pragma unroll
            for (int t2 = 0; t2 < 2; ++t2)
                #pragma unroll
                for (int r = 0; r < 16; r += 4) {
                    const float p0 = EXP2(st[t2][r+0] - mrun);
                    const float p1 = EXP2(st[t2][r+1] - mrun);
                    const float p2 = EXP2(st[t2][r+2] - mrun);
                    const float p3 = EXP2(st[t2][r+3] - mrun);
                    st[t2][r+0] = p0; st[t2][r+1] = p1;
                    st[t2][r+2] = p2; st[t2][r+3] = p3;
                    ps0 += p0; ps1 += p1; ps2 += p2; ps3 += p3;
                }
            float psum = (ps0 + ps1) + (ps2 + ps3);
            psum += __shfl_xor(psum, 32);
            lrun += psum;

            // ---- P -> bf16 (cvt_pk) + permlane32_swap, feed PV ----
            __builtin_amdgcn_s_setprio(1);
            #pragma unroll
            for (int kt = 0; kt < 4; ++kt) {
                const int t2 = kt >> 1, base = (kt & 1) * 8;
                const uint32_t A0 = cvt_pk_bf16(st[t2][base+0], st[t2][base+1]);
                const uint32_t B0 = cvt_pk_bf16(st[t2][base+4], st[t2][base+5]);
                const uint32_t A1 = cvt_pk_bf16(st[t2][base+2], st[t2][base+3]);
                const uint32_t B1 = cvt_pk_bf16(st[t2][base+6], st[t2][base+7]);
                uint32_t u0, u1, u2, u3;
                pl32swap(A0, B0, hi, u0, u2);
                pl32swap(A1, B1, hi, u1, u3);
                union { uint32_t u[4]; s16x8 v; } pa;
                pa.u[0] = u0; pa.u[1] = u1; pa.u[2] = u2; pa.u[3] = u3;
                #pragma unroll
                for (int c = 0; c < 2; ++c) {
                    const int d = 32*c + l31;
                    const s16x8 vf = *(const s16x8*)(Vd + ((d*128 + kt*32 + hi*16) ^ ((d & 7) << 4)));
                    acc[c] = __builtin_amdgcn_mfma_f32_32x32x16_bf16(vf, pa.v, acc[c], 0, 0, 0);
                }
            }
            __builtin_amdgcn_s_setprio(0);
        }
        __syncthreads();
        cur ^= 1;
    }

    // ---- epilogue: O^T -> O via padded LDS bounce (aliases staging buffers) ----
    float (*ob)[68] = (float(*)[68])smem;
    const float inv = 1.0f / lrun;
    #pragma unroll
    for (int chunk = 0; chunk < 2; ++chunk) {
        __syncthreads();
        if ((w >> 1) == chunk) {
            const int qloc = 32*(w & 1) + l31;
            #pragma unroll
            for (int c = 0; c < 2; ++c)
                #pragma unroll
                for (int r = 0; r < 16; ++r) {
                    const int d = 32*c + (r & 3) + 8*(r >> 2) + 4*hi;
                    ob[qloc][d] = acc[c][r] * inv;
                }
        }
        __syncthreads();
        #pragma unroll
        for (int i = 0; i < 4; ++i) {
            const int idx = i*256 + tid;
            const int row = idx >> 4;
            const int c4  = (idx & 15) * 4;
            const float4 v = *(const float4*)&ob[row][c4];
            *(float4*)(Op + (size_t)(q0 + chunk*64 + row) * Dd + c4) = v;
        }
    }
}

// ---------------- fallback (round-2 kernel, used only if ws too small) ----------------
__global__ __launch_bounds__(256)
void attn_fwd_fb(const float* __restrict__ Qg, const float* __restrict__ Kg,
                 const float* __restrict__ Vg, float* __restrict__ Og) {
    const int qb   = (int)gridDim.x - 1 - (int)blockIdx.x;
    const int q0   = qb * QBLK;
    const int bh   = blockIdx.y;
    const int tid  = threadIdx.x;
    const int w    = tid >> 6;
    const int l    = tid & 63;
    const int l31  = l & 31;
    const int hi   = l >> 5;
    const int qmin = q0 + 32 * w;
    const int qrow = qmin + l31;

    __shared__ short Ks[KVB * Dd];
    __shared__ short Vs[Dd * KVB];
    __shared__ float ob[64][68];

    const size_t base = (size_t)bh * Ss * Dd;
    const float* Qp = Qg + base;
    const float* Kp = Kg + base;
    const float* Vp = Vg + base;
    float*       Op = Og + base;

    const float SCALE = 0.18033688011112042f;
    s16x8 qf[4];
    {
        const float* qp = Qp + (size_t)qrow * Dd;
        #pragma unroll
        for (int kt = 0; kt < 4; ++kt) {
            const float4 a = *(const float4*)(qp + kt*16 + hi*8);
            const float4 b = *(const float4*)(qp + kt*16 + hi*8 + 4);
            s16x8 q8;
            q8[0]=f2bf(a.x*SCALE); q8[1]=f2bf(a.y*SCALE); q8[2]=f2bf(a.z*SCALE); q8[3]=f2bf(a.w*SCALE);
            q8[4]=f2bf(b.x*SCALE); q8[5]=f2bf(b.y*SCALE); q8[6]=f2bf(b.z*SCALE); q8[7]=f2bf(b.w*SCALE);
            qf[kt] = q8;
        }
    }

    f32x16 acc[2];
    #pragma unroll
    for (int c = 0; c < 2; ++c)
        #pragma unroll
        for (int r = 0; r < 16; ++r) acc[c][r] = 0.f;
    float mrun = -1e30f, lrun = 0.f;

    const int skv = tid >> 2;
    const int sd  = (tid & 3) * 16;
    const int vd  = tid & 63;
    const int vo  = (tid >> 6) * 8;

    char* KB = (char*)Ks;
    char* VB = (char*)Vs;

    for (int kv0 = 0; kv0 < q0 + QBLK; kv0 += KVB) {
        __syncthreads();
        {
            const float* kr = Kp + (size_t)(kv0 + skv) * Dd + sd;
            const float4 a  = *(const float4*)(kr);
            const float4 b  = *(const float4*)(kr + 4);
            const float4 c4 = *(const float4*)(kr + 8);
            const float4 d4 = *(const float4*)(kr + 12);
            s16x8 lo8, hi8;
            lo8[0]=f2bf(a.x);  lo8[1]=f2bf(a.y);  lo8[2]=f2bf(a.z);  lo8[3]=f2bf(a.w);
            lo8[4]=f2bf(b.x);  lo8[5]=f2bf(b.y);  lo8[6]=f2bf(b.z);  lo8[7]=f2bf(b.w);
            hi8[0]=f2bf(c4.x); hi8[1]=f2bf(c4.y); hi8[2]=f2bf(c4.z); hi8[3]=f2bf(c4.w);
            hi8[4]=f2bf(d4.x); hi8[5]=f2bf(d4.y); hi8[6]=f2bf(d4.z); hi8[7]=f2bf(d4.w);
            const int bse = skv*128 + sd*2;
            const int sw  = (skv & 7) << 4;
            *(s16x8*)(KB + ((bse)      ^ sw)) = lo8;
            *(s16x8*)(KB + ((bse + 16) ^ sw)) = hi8;
        }
        #pragma unroll
        for (int h = 0; h < 2; ++h) {
            const int kvb = h * 32 + vo;
            const float* vr = Vp + (size_t)(kv0 + kvb) * Dd + vd;
            float vv[8];
            #pragma unroll
            for (int r = 0; r < 8; ++r) vv[r] = vr[(size_t)r * Dd];
            s16x8 v8;
            #pragma unroll
            for (int r = 0; r < 8; ++r) v8[r] = f2bf(vv[r]);
            *(s16x8*)(VB + ((vd*128 + kvb*2) ^ ((vd & 7) << 4))) = v8;
        }
        __syncthreads();

        if (kv0 <= qmin + 31) {
            f32x16 st[2];
            #pragma unroll
            for (int t2 = 0; t2 < 2; ++t2) {
                #pragma unroll
                for (int r = 0; r < 16; ++r) st[t2][r] = 0.f;
                const int kvr = t2*32 + l31;
                const int sw  = (kvr & 7) << 4;
                #pragma unroll
                for (int kt = 0; kt < 4; ++kt) {
                    const s16x8 kf = *(const s16x8*)(KB + ((kvr*128 + kt*32 + hi*16) ^ sw));
                    st[t2] = __builtin_amdgcn_mfma_f32_32x32x16_bf16(kf, qf[kt], st[t2], 0, 0, 0);
                }
            }
            if (kv0 + 63 > qmin) {
                #pragma unroll
                for (int t2 = 0; t2 < 2; ++t2)
                    #pragma unroll
                    for (int r = 0; r < 16; ++r) {
                        const int kvloc = 32*t2 + (r & 3) + 8*(r >> 2) + 4*hi;
                        if (kv0 + kvloc > qrow) st[t2][r] = -1e30f;
                    }
            }
            float pmax = st[0][0];
            #pragma unroll
            for (int t2 = 0; t2 < 2; ++t2)
                #pragma unroll
                for (int r = 0; r < 16; ++r) pmax = fmaxf(pmax, st[t2][r]);
            pmax = fmaxf(pmax, __shfl_xor(pmax, 32));
            const float newm = fmaxf(mrun, pmax);
            const float corr = EXP2(mrun - newm);
            mrun = newm;
            float psum = 0.f;
            #pragma unroll
            for (int t2 = 0; t2 < 2; ++t2)
                #pragma unroll
                for (int r = 0; r < 16; ++r) {
                    const float p = EXP2(st[t2][r] - mrun);
                    st[t2][r] = p;
                    psum += p;
                }
            psum += __shfl_xor(psum, 32);
            lrun = lrun * corr + psum;
            #pragma unroll
            for (int c = 0; c < 2; ++c)
                #pragma unroll
                for (int r = 0; r < 16; ++r) acc[c][r] *= corr;

            #pragma unroll
            for (int kt = 0; kt < 4; ++kt) {
                const int t2 = kt >> 1, base2 = (kt & 1) * 8;
                const uint32_t A0 = cvt_pk_bf16(st[t2][base2+0], st[t2][base2+1]);
                const uint32_t B0 = cvt_pk_bf16(st[t2][base2+4], st[t2][base2+5]);
                const uint32_t A1 = cvt_pk_bf16(st[t2][base2+2], st[t2][base2+3]);
                const uint32_t B1 = cvt_pk_bf16(st[t2][base2+6], st[t2][base2+7]);
                uint32_t u0, u1, u2, u3;
                pl32swap(A0, B0, hi, u0, u2);
                pl32swap(A1, B1, hi, u1, u3);
                union { uint32_t u[4]; s16x8 v; } pa;
                pa.u[0] = u0; pa.u[1] = u1; pa.u[2] = u2; pa.u[3] = u3;
                #pragma unroll
                for (int c = 0; c < 2; ++c) {
                    const int d  = 32*c + l31;
                    const s16x8 vf = *(const s16x8*)(VB + ((d*128 + kt*32 + hi*16) ^ ((d & 7) << 4)));
                    acc[c] = __builtin_amdgcn_mfma_f32_32x32x16_bf16(vf, pa.v, acc[c], 0, 0, 0);
                }
            }
        }
    }

    const float inv = 1.0f / lrun;
    #pragma unroll
    for (int chunk = 0; chunk < 2; ++chunk) {
        __syncthreads();
        if ((w >> 1) == chunk) {
            const int qloc = 32*(w & 1) + l31;
            #pragma unroll
            for (int c = 0; c < 2; ++c)
                #pragma unroll
                for (int r = 0; r < 16; ++r) {
                    const int d = 32*c + (r & 3) + 8*(r >> 2) + 4*hi;
                    ob[qloc][d] = acc[c][r] * inv;
                }
        }
        __syncthreads();
        #pragma unroll
        for (int i = 0; i < 4; ++i) {
            const int idx = i*256 + tid;
            const int row = idx >> 4;
            const int c4  = (idx & 15) * 4;
            const float4 v = *(const float4*)&ob[row][c4];
            *(float4*)(Op + (size_t)(q0 + chunk*64 + row) * Dd + c4) = v;
        }
    }
}

extern "C" void kernel_launch(void* const* d_in, const int* in_sizes, int n_in,
                              void* d_out, int out_size, void* d_ws, size_t ws_size,
                              hipStream_t stream) {
    const float* Q = (const float*)d_in[0];
    const float* K = (const float*)d_in[1];
    const float* V = (const float*)d_in[2];
    float* O = (float*)d_out;
    const size_t nelem = (size_t)NBH * Ss * Dd;           // 8388608
    const size_t need  = 2 * nelem * sizeof(uint16_t);    // 32 MiB

    if (ws_size >= need) {
        uint16_t* Kb = (uint16_t*)d_ws;
        uint16_t* Vt = Kb + nelem;
        cvt_k_kernel<<<dim3((unsigned)(nelem / 8 / 256)), 256, 0, stream>>>(K, Kb);
        tr_v_kernel<<<dim3(Ss / 64, NBH), 256, 0, stream>>>(V, Vt);
        attn_fwd_main<<<dim3(Ss / QBLK, NBH), 256, 0, stream>>>(Q, Kb, Vt, O);
    } else {
        attn_fwd_fb<<<dim3(Ss / QBLK, NBH), 256, 0, stream>>>(Q, K, V, O);
    }
}

// Round 4
// 193.114 us; speedup vs baseline: 2.1453x; 1.0577x over previous
//
#include <hip/hip_runtime.h>
#include <hip/hip_bf16.h>
#include <stdint.h>

#define Ss 2048
#define Dd 64
#define NBH 64     // B*H
#define NQT 32     // 64-row q-tiles

using f32x16 = __attribute__((ext_vector_type(16))) float;
using s16x8  = __attribute__((ext_vector_type(8))) short;

#if __has_builtin(__builtin_amdgcn_exp2f)
#define EXP2(x) __builtin_amdgcn_exp2f(x)
#else
#define EXP2(x) exp2f(x)
#endif

__device__ __forceinline__ uint32_t cvt_pk_bf16(float lo, float hi) {
    uint32_t r;
    asm("v_cvt_pk_bf16_f32 %0, %1, %2" : "=v"(r) : "v"(lo), "v"(hi));
    return r;
}

// HW half-swap: a := {a_lo, b_lo}, b := {a_hi, b_hi}
__device__ __forceinline__ void pls(uint32_t& a, uint32_t& b) {
#if __has_builtin(__builtin_amdgcn_permlane32_swap)
    auto r = __builtin_amdgcn_permlane32_swap(a, b, false, false);
    a = r[0]; b = r[1];
#else
    asm("v_permlane32_swap_b32 %0, %1" : "+v"(a), "+v"(b));
#endif
}
__device__ __forceinline__ float xhalf_max(float x) {
    union { float f; uint32_t u; } a, b;
    a.f = x; b.f = x;
    pls(a.u, b.u);
    return fmaxf(a.f, b.f);
}
__device__ __forceinline__ float xhalf_add(float x) {
    union { float f; uint32_t u; } a, b;
    a.f = x; b.f = x;
    pls(a.u, b.u);
    return a.f + b.f;
}

// ---------------- fused prepass: K fp32->bf16 (same layout) + V -> V^T bf16 [bh][d][kv] ----------------
__global__ __launch_bounds__(256)
void prep_kv(const float* __restrict__ K, const float* __restrict__ V,
             uint16_t* __restrict__ Kb, uint16_t* __restrict__ Vt) {
    const int bh  = blockIdx.y;
    const int kv0 = blockIdx.x * 64;
    __shared__ float ts[64][65];
    const size_t off = (size_t)bh * Ss * Dd + (size_t)kv0 * Dd;

    // K convert: thread r=tid>>2 handles 16 cols
    {
        const int r = threadIdx.x >> 2;
        const int c = (threadIdx.x & 3) * 16;
        const float* kp = K + off + (size_t)r * Dd + c;
        const float4 a  = *(const float4*)(kp);
        const float4 b  = *(const float4*)(kp + 4);
        const float4 c4 = *(const float4*)(kp + 8);
        const float4 d4 = *(const float4*)(kp + 12);
        union { uint32_t u[8]; struct { s16x8 a, b; } s; } o;
        o.u[0] = cvt_pk_bf16(a.x, a.y);  o.u[1] = cvt_pk_bf16(a.z, a.w);
        o.u[2] = cvt_pk_bf16(b.x, b.y);  o.u[3] = cvt_pk_bf16(b.z, b.w);
        o.u[4] = cvt_pk_bf16(c4.x, c4.y); o.u[5] = cvt_pk_bf16(c4.z, c4.w);
        o.u[6] = cvt_pk_bf16(d4.x, d4.y); o.u[7] = cvt_pk_bf16(d4.z, d4.w);
        uint16_t* op = Kb + off + (size_t)r * Dd + c;
        *(s16x8*)op       = o.s.a;
        *(s16x8*)(op + 8) = o.s.b;
    }

    // V transpose via LDS bounce
    const float* vp = V + off;
    {
        const int r = threadIdx.x >> 2;
        const int c = (threadIdx.x & 3) * 16;
        #pragma unroll
        for (int j = 0; j < 4; ++j)
            *(float4*)&ts[r][c + 4*j] = *(const float4*)(vp + (size_t)r * Dd + c + 4*j);
    }
    __syncthreads();
    {
        const int d   = threadIdx.x >> 2;
        const int k16 = (threadIdx.x & 3) * 16;
        union { uint32_t u[8]; struct { s16x8 a, b; } s; } o;
        #pragma unroll
        for (int j = 0; j < 8; ++j)
            o.u[j] = cvt_pk_bf16(ts[k16 + 2*j][d], ts[k16 + 2*j + 1][d]);
        uint16_t* op = Vt + ((size_t)bh * Dd + d) * Ss + kv0 + k16;
        *(s16x8*)op       = o.s.a;
        *(s16x8*)(op + 8) = o.s.b;
    }
}

// ---------------- main: paired causal blocks, 2 waves x 32 q-rows ----------------
__global__ __launch_bounds__(128, 2)
void attn_fwd_main(const float* __restrict__ Qg, const uint16_t* __restrict__ Kb,
                   const uint16_t* __restrict__ Vt, float* __restrict__ Og) {
    const int qbp = blockIdx.x;          // pair 0..15 -> q-tiles {31-qbp, qbp}
    const int bh  = blockIdx.y;
    const int tid = threadIdx.x;
    const int w   = tid >> 6;            // 0..1
    const int l   = tid & 63;
    const int l31 = l & 31;
    const int hi  = l >> 5;

    __shared__ char smem[2 * 16384];     // 2 x (K 8KB + V 8KB); epilogue aliases

    const float* Qp = Qg + (size_t)bh * Ss * Dd;
    const char*  Kp = (const char*)(Kb + (size_t)bh * Ss * Dd);
    const char*  Vp = (const char*)(Vt + (size_t)bh * Dd * Ss);
    float*       Op = Og + (size_t)bh * Ss * Dd;

    const int rK = l >> 3;               // row within 8-row chunk
    const int bX = (l & 7) ^ rK;         // inverse-swizzled 16B slot

    const float SCALE = 0.18033688011112042f;  // (1/sqrt(64)) * log2(e)

    for (int half = 0; half < 2; ++half) {
        const int qt   = half ? qbp : (NQT - 1 - qbp);
        const int q0   = qt * 64;
        const int qmin = q0 + 32 * w;
        const int qrow = qmin + l31;
        const int nt   = qt + 1;

        // ---- Q fragments (B-operand of swapped QK^T) ----
        s16x8 qf[4];
        {
            const float* qp = Qp + (size_t)qrow * Dd;
            #pragma unroll
            for (int kt = 0; kt < 4; ++kt) {
                const float4 a = *(const float4*)(qp + kt*16 + hi*8);
                const float4 b = *(const float4*)(qp + kt*16 + hi*8 + 4);
                union { uint32_t u[4]; s16x8 v; } q;
                q.u[0] = cvt_pk_bf16(a.x*SCALE, a.y*SCALE);
                q.u[1] = cvt_pk_bf16(a.z*SCALE, a.w*SCALE);
                q.u[2] = cvt_pk_bf16(b.x*SCALE, b.y*SCALE);
                q.u[3] = cvt_pk_bf16(b.z*SCALE, b.w*SCALE);
                qf[kt] = q.v;
            }
        }

        f32x16 acc[2];
        #pragma unroll
        for (int c = 0; c < 2; ++c)
            #pragma unroll
            for (int r = 0; r < 16; ++r) acc[c][r] = 0.f;
        float mrun = -1e30f, lrun = 0.f;

        auto STAGE = [&](int t, int buf) {
            char* Kd = smem + buf * 16384;
            char* Vd = Kd + 8192;
            #pragma unroll
            for (int c2 = 0; c2 < 4; ++c2) {
                const int c = 4 * w + c2;                         // chunk 0..7
                const char* gk = Kp + (size_t)(t*64 + c*8 + rK) * 128 + bX * 16;
                const char* gv = Vp + (size_t)(c*8 + rK) * (Ss*2) + t*128 + bX * 16;
#if __has_builtin(__builtin_amdgcn_global_load_lds)
                __builtin_amdgcn_global_load_lds((const uint32_t*)gk, (uint32_t*)(Kd + c*1024), 16, 0, 0);
                __builtin_amdgcn_global_load_lds((const uint32_t*)gv, (uint32_t*)(Vd + c*1024), 16, 0, 0);
#else
                *(s16x8*)(Kd + c*1024 + l*16) = *(const s16x8*)gk;
                *(s16x8*)(Vd + c*1024 + l*16) = *(const s16x8*)gv;
#endif
            }
        };

        __syncthreads();                 // protect smem (prev half epilogue) before restaging
        STAGE(0, 0);
        __syncthreads();
        int cur = 0;

        for (int t = 0; t < nt; ++t) {
            if (t + 1 < nt) STAGE(t + 1, cur ^ 1);
            const int kv0 = t * 64;
            const char* Kd = smem + cur * 16384;
            const char* Vd = Kd + 8192;

            // ---- S^T = K @ Q^T (log2 domain) ----
            f32x16 st[2];
            __builtin_amdgcn_s_setprio(1);
            #pragma unroll
            for (int t2 = 0; t2 < 2; ++t2) {
                #pragma unroll
                for (int r = 0; r < 16; ++r) st[t2][r] = 0.f;
                const int kvr = t2 * 32 + l31;
                const int sw  = (kvr & 7) << 4;
                #pragma unroll
                for (int kt = 0; kt < 4; ++kt) {
                    const s16x8 kf = *(const s16x8*)(Kd + ((kvr*128 + kt*32 + hi*16) ^ sw));
                    st[t2] = __builtin_amdgcn_mfma_f32_32x32x16_bf16(kf, qf[kt], st[t2], 0, 0, 0);
                }
            }
            __builtin_amdgcn_s_setprio(0);

            // ---- causal mask (diagonal tile only) ----
            if (kv0 + 63 > qmin) {
                #pragma unroll
                for (int t2 = 0; t2 < 2; ++t2)
                    #pragma unroll
                    for (int r = 0; r < 16; ++r) {
                        const int kvloc = 32*t2 + (r & 3) + 8*(r >> 2) + 4*hi;
                        if (kv0 + kvloc > qrow) st[t2][r] = -1e30f;
                    }
            }

            // ---- online softmax (permlane cross-half, no LDS ops) ----
            float mx0 = st[0][0], mx1 = st[0][1], mx2 = st[0][2], mx3 = st[0][3];
            #pragma unroll
            for (int t2 = 0; t2 < 2; ++t2)
                #pragma unroll
                for (int r = (t2 ? 0 : 4); r < 16; r += 4) {
                    mx0 = fmaxf(mx0, st[t2][r+0]); mx1 = fmaxf(mx1, st[t2][r+1]);
                    mx2 = fmaxf(mx2, st[t2][r+2]); mx3 = fmaxf(mx3, st[t2][r+3]);
                }
            float pmax = fmaxf(fmaxf(mx0, mx1), fmaxf(mx2, mx3));
            pmax = xhalf_max(pmax);

            if (!__all(pmax - mrun <= 11.f)) {   // T13 defer-max (log2 THR)
                const float newm = fmaxf(mrun, pmax);
                const float corr = EXP2(mrun - newm);
                mrun = newm;
                lrun *= corr;
                acc[0] *= corr;
                acc[1] *= corr;
            }

            float ps0 = 0.f, ps1 = 0.f, ps2 = 0.f, ps3 = 0.f;
            #pragma unroll
            for (int t2 = 0; t2 < 2; ++t2)
                #pragma unroll
                for (int r = 0; r < 16; r += 4) {
                    const float p0 = EXP2(st[t2][r+0] - mrun);
                    const float p1 = EXP2(st[t2][r+1] - mrun);
                    const float p2 = EXP2(st[t2][r+2] - mrun);
                    const float p3 = EXP2(st[t2][r+3] - mrun);
                    st[t2][r+0] = p0; st[t2][r+1] = p1;
                    st[t2][r+2] = p2; st[t2][r+3] = p3;
                    ps0 += p0; ps1 += p1; ps2 += p2; ps3 += p3;
                }
            lrun += xhalf_add((ps0 + ps1) + (ps2 + ps3));

            // ---- P -> bf16 + permlane32_swap, feed PV ----
            __builtin_amdgcn_s_setprio(1);
            #pragma unroll
            for (int kt = 0; kt < 4; ++kt) {
                const int t2 = kt >> 1, base = (kt & 1) * 8;
                uint32_t u0 = cvt_pk_bf16(st[t2][base+0], st[t2][base+1]);
                uint32_t u2 = cvt_pk_bf16(st[t2][base+4], st[t2][base+5]);
                uint32_t u1 = cvt_pk_bf16(st[t2][base+2], st[t2][base+3]);
                uint32_t u3 = cvt_pk_bf16(st[t2][base+6], st[t2][base+7]);
                pls(u0, u2);
                pls(u1, u3);
                union { uint32_t u[4]; s16x8 v; } pa;
                pa.u[0] = u0; pa.u[1] = u1; pa.u[2] = u2; pa.u[3] = u3;
                #pragma unroll
                for (int c = 0; c < 2; ++c) {
                    const int d = 32*c + l31;
                    const s16x8 vf = *(const s16x8*)(Vd + ((d*128 + kt*32 + hi*16) ^ ((d & 7) << 4)));
                    acc[c] = __builtin_amdgcn_mfma_f32_32x32x16_bf16(vf, pa.v, acc[c], 0, 0, 0);
                }
            }
            __builtin_amdgcn_s_setprio(0);

            __syncthreads();
            cur ^= 1;
        }

        // ---- epilogue: O^T -> O via padded LDS bounce ----
        float (*ob)[68] = (float(*)[68])smem;
        const float inv = 1.0f / lrun;
        {
            const int qloc = 32*w + l31;
            #pragma unroll
            for (int c = 0; c < 2; ++c)
                #pragma unroll
                for (int r = 0; r < 16; ++r) {
                    const int d = 32*c + (r & 3) + 8*(r >> 2) + 4*hi;
                    ob[qloc][d] = acc[c][r] * inv;
                }
        }
        __syncthreads();
        #pragma unroll
        for (int i = 0; i < 8; ++i) {
            const int idx = i*128 + tid;
            const int row = idx >> 4;
            const int c4  = (idx & 15) * 4;
            const float4 v = *(const float4*)&ob[row][c4];
            *(float4*)(Op + (size_t)(q0 + row) * Dd + c4) = v;
        }
        // loop-top __syncthreads protects smem before next half's staging
    }
}

extern "C" void kernel_launch(void* const* d_in, const int* in_sizes, int n_in,
                              void* d_out, int out_size, void* d_ws, size_t ws_size,
                              hipStream_t stream) {
    const float* Q = (const float*)d_in[0];
    const float* K = (const float*)d_in[1];
    const float* V = (const float*)d_in[2];
    float* O = (float*)d_out;
    const size_t nelem = (size_t)NBH * Ss * Dd;           // 8388608
    const size_t need  = 2 * nelem * sizeof(uint16_t);    // 32 MiB

    uint16_t* Kb = (uint16_t*)d_ws;
    uint16_t* Vt = Kb + nelem;
    (void)need; (void)ws_size;
    prep_kv<<<dim3(Ss / 64, NBH), 256, 0, stream>>>(K, V, Kb, Vt);
    attn_fwd_main<<<dim3(NQT / 2, NBH), 128, 0, stream>>>(Q, Kb, Vt, O);
}